// Round 8
// baseline (345.934 us; speedup 1.0000x reference)
//
#include <hip/hip_runtime.h>

#define LOG2E 1.4426950408889634f
#define BN_EPS 1e-5f

// ws float offsets
#define WS_W1P   32     // 162: prescaled W1'' = sc1 ∘ W1
#define WS_B1P   200    // 18:  b1'' = be1 - sc1*m1
#define WS_BN2S  224    // 9
#define WS_BN2H  240    // 9
#define WS_L1    256    // per dir (stride 32): w[8], u[16], b[8]  (exp2-prescaled)
#define WS_L2    320    // per dir (stride 24): W[16], U[4], b[4]  (exp2-prescaled)
#define WS_TICK  384    // 2 int tickets (byte offset 1536)
#define WS_PART1 1024   // [nbp1][64] moment partials
#define WS_PART2 66560  // [nbp2][32] z2-stat partials
#define WS_Z2    131072 // z2 cache, col-major [9][B]

__device__ __forceinline__ float relu_(float x){ return fmaxf(x, 0.f); }

__device__ __forceinline__ float wsum(float v){
    #pragma unroll
    for (int m = 32; m >= 1; m >>= 1) v += __shfl_xor(v, m, 64);
    return v;
}

__device__ constexpr int TRI(int j, int l){ return j*9 - j*(j-1)/2 + (l - j); }

__device__ __forceinline__ void load_h0(const float* __restrict__ x, const float* __restrict__ emb,
                                        long row, float h0[9])
{
    const float4* xv = (const float4*)(x + row * 8);
    float4 p = xv[0];
    float4 q = xv[1];
    int idx = (int)p.x;
    float2 e = ((const float2*)emb)[idx];
    h0[0] = e.x; h0[1] = e.y;
    h0[2] = p.y; h0[3] = p.z; h0[4] = p.w;
    h0[5] = q.x; h0[6] = q.y; h0[7] = q.z; h0[8] = q.w;
}

// LSTM cell, pre-scaled z's: zi,zo scaled +log2e; zf scaled -log2e; zg scaled +2*log2e.
__device__ __forceinline__ float cellh(float zi, float zfn, float zg2, float zo, float& c){
    float A  = __builtin_amdgcn_exp2f(zi);
    float G  = __builtin_amdgcn_exp2f(zg2);
    float icg = A * (G - 1.f) * __builtin_amdgcn_rcpf((1.f + A) * (1.f + G));   // sig(i)*tanh(g)
    float Fp = __builtin_amdgcn_exp2f(zfn);
    float fs = __builtin_amdgcn_rcpf(1.f + Fp);                                  // sig(f)
    c = fmaf(fs, c, icg);
    float O  = __builtin_amdgcn_exp2f(zo);
    float T  = __builtin_amdgcn_exp2f((2.f * LOG2E) * c);
    return O * (T - 1.f) * __builtin_amdgcn_rcpf((1.f + O) * (1.f + T));         // sig(o)*tanh(c)
}

struct KParams {
    const float *x, *emb, *W1, *b1, *g1, *be1, *W2, *b2, *g2, *be2;
    const float *w1f, *u1f, *c1f, *w1r, *u1r, *c1r;
    const float *w2f, *u2f, *c2f, *w2r, *u2r, *c2r;
    float* ws;
    float* out;
    int B;
    int nbp1;
    int nbp2;
};

// ============ k1: h0 moment partials -> tail: BN1 consts + prescaled weights ============
__global__ __launch_bounds__(256) void k1(KParams p)
{
    const int tid = threadIdx.x;
    float s9[9], mt[45];
    #pragma unroll
    for (int j = 0; j < 9; ++j) s9[j] = 0.f;
    #pragma unroll
    for (int t = 0; t < 45; ++t) mt[t] = 0.f;

    const long sweep = (long)gridDim.x * 2048;
    for (long b0 = (long)blockIdx.x * 2048; b0 < p.B; b0 += sweep){
        #pragma unroll
        for (int r = 0; r < 8; ++r){
            long row = b0 + tid + r * 256;
            if (row < p.B){
                float h0[9];
                load_h0(p.x, p.emb, row, h0);
                #pragma unroll
                for (int j = 0; j < 9; ++j){
                    s9[j] += h0[j];
                    #pragma unroll
                    for (int l = j; l < 9; ++l)
                        mt[TRI(j,l)] = fmaf(h0[j], h0[l], mt[TRI(j,l)]);
                }
            }
        }
    }
    __shared__ float sm[54];
    if (tid < 54) sm[tid] = 0.f;
    __syncthreads();
    bool l0 = (tid & 63) == 0;
    #pragma unroll
    for (int j = 0; j < 9; ++j){
        float v = wsum(s9[j]);
        if (l0) atomicAdd(&sm[j], v);
    }
    #pragma unroll
    for (int t = 0; t < 45; ++t){
        float v = wsum(mt[t]);
        if (l0) atomicAdd(&sm[9 + t], v);
    }
    __syncthreads();
    float* part1 = p.ws + WS_PART1;
    if (tid < 54) part1[(long)blockIdx.x * 64 + tid] = sm[tid];

    // ---- ticket: last block becomes the reducer ----
    __threadfence();
    __shared__ int lastFlag;
    if (tid == 0){
        int t = __hip_atomic_fetch_add((int*)(p.ws + WS_TICK), 1,
                                       __ATOMIC_ACQ_REL, __HIP_MEMORY_SCOPE_AGENT);
        lastFlag = (t == (int)gridDim.x - 1);
    }
    __syncthreads();
    if (!lastFlag) return;

    // ---- tail: reduce partials ----
    __shared__ float red[4][64];
    {
        int c = tid & 63, seg = tid >> 6;
        int per = (p.nbp1 + 3) >> 2;
        float s = 0.f;
        for (int i = 0; i < per; ++i){
            int b = seg * per + i;
            if (b < p.nbp1)
                s += __hip_atomic_load(&part1[(long)b * 64 + c], __ATOMIC_RELAXED, __HIP_MEMORY_SCOPE_AGENT);
        }
        red[seg][c] = s;
    }
    __syncthreads();
    __shared__ float tot[54];
    __shared__ float scs[18];
    if (tid < 54) tot[tid] = red[0][tid] + red[1][tid] + red[2][tid] + red[3][tid];
    __syncthreads();

    const float invB = 1.f / (float)p.B;
    if (tid < 18){
        int k = tid;
        float w[9];
        #pragma unroll
        for (int j = 0; j < 9; ++j) w[j] = p.W1[k*9 + j];
        float dot9 = 0.f, q = 0.f;
        #pragma unroll
        for (int j = 0; j < 9; ++j){
            dot9 = fmaf(w[j], tot[j], dot9);
            q = fmaf(w[j]*w[j], tot[9 + TRI(j,j)], q);
            #pragma unroll
            for (int l = j+1; l < 9; ++l)
                q = fmaf(2.f*w[j]*w[l], tot[9 + TRI(j,l)], q);
        }
        float m1  = dot9 * invB;
        float var = fmaf(-m1, m1, q * invB);
        float sc  = p.g1[k] * __builtin_amdgcn_rsqf(var + BN_EPS);
        scs[k] = sc;
        p.ws[WS_B1P + k] = fmaf(-sc, m1, p.be1[k]);   // b1 cancels algebraically
    }
    // LSTM weight prep (independent of stats)
    const float scl[4] = { LOG2E, -LOG2E, 2.f*LOG2E, LOG2E };  // i, f, g, o
    if (tid >= 64 && tid < 80){
        int r = tid - 64;
        int dir = r >> 3, rr = r & 7;
        const float* W = dir ? p.w1r : p.w1f;
        const float* U = dir ? p.u1r : p.u1f;
        const float* Bb = dir ? p.c1r : p.c1f;
        float sc = scl[rr >> 1];
        float* dst = p.ws + WS_L1 + dir * 32;
        dst[rr]            = sc * W[rr];
        dst[8 + 2*rr]      = sc * U[2*rr];
        dst[8 + 2*rr + 1]  = sc * U[2*rr + 1];
        dst[24 + rr]       = sc * Bb[rr];
    } else if (tid >= 80 && tid < 88){
        int r = tid - 80;
        int dir = r >> 2, rr = r & 3;
        const float* W = dir ? p.w2r : p.w2f;
        const float* U = dir ? p.u2r : p.u2f;
        const float* Bb = dir ? p.c2r : p.c2f;
        float sc = scl[rr];
        float* dst = p.ws + WS_L2 + dir * 24;
        #pragma unroll
        for (int j = 0; j < 4; ++j) dst[4*rr + j] = sc * W[4*rr + j];
        dst[16 + rr] = sc * U[rr];
        dst[20 + rr] = sc * Bb[rr];
    }
    __syncthreads();
    for (int e = tid; e < 162; e += 256){
        int k = e / 9;
        p.ws[WS_W1P + e] = scs[k] * p.W1[e];
    }
}

// ============ k2: a1 -> z2 store + stat partials -> tail: BN2 consts ============
template<int STORE_Z2>
__global__ __launch_bounds__(256) void k2(KParams p)
{
    const int tid = threadIdx.x;
    __shared__ float lw[352];
    for (int e = tid; e < 351; e += 256){
        float v;
        if (e < 162)       v = p.ws[WS_W1P + e];
        else if (e < 180)  v = p.ws[WS_B1P + (e - 162)];
        else if (e < 342)  v = p.W2[e - 180];
        else               v = p.b2[e - 342];
        lw[e] = v;
    }
    __syncthreads();
    const float* lW1 = lw;
    const float* lb1 = lw + 162;
    const float* lW2 = lw + 180;
    const float* lb2 = lw + 342;

    float as[9], aq[9];
    #pragma unroll
    for (int k = 0; k < 9; ++k){ as[k] = 0.f; aq[k] = 0.f; }

    float* z2buf = p.ws + WS_Z2;
    const long sweep = (long)gridDim.x * 1024;
    for (long b0 = (long)blockIdx.x * 1024; b0 < p.B; b0 += sweep){
        #pragma unroll
        for (int r = 0; r < 4; ++r){
            long row = b0 + tid + r * 256;
            if (row < p.B){
                float h0[9];
                load_h0(p.x, p.emb, row, h0);
                float a1[18];
                #pragma unroll
                for (int k = 0; k < 18; ++k){
                    float s = lb1[k];
                    #pragma unroll
                    for (int j = 0; j < 9; ++j) s = fmaf(lW1[k*9 + j], h0[j], s);
                    a1[k] = relu_(s);
                }
                #pragma unroll
                for (int k = 0; k < 9; ++k){
                    float s = lb2[k];
                    #pragma unroll
                    for (int j = 0; j < 18; ++j) s = fmaf(lW2[k*18 + j], a1[j], s);
                    if (STORE_Z2) z2buf[(long)k * p.B + row] = s;
                    as[k] += s; aq[k] = fmaf(s, s, aq[k]);
                }
            }
        }
    }
    __shared__ float sm2[18];
    if (tid < 18) sm2[tid] = 0.f;
    __syncthreads();
    bool l0 = (tid & 63) == 0;
    #pragma unroll
    for (int k = 0; k < 9; ++k){
        float s = wsum(as[k]);
        float q = wsum(aq[k]);
        if (l0){ atomicAdd(&sm2[k], s); atomicAdd(&sm2[9 + k], q); }
    }
    __syncthreads();
    float* part2 = p.ws + WS_PART2;
    if (tid < 18) part2[(long)blockIdx.x * 32 + tid] = sm2[tid];

    // ---- ticket ----
    __threadfence();
    __shared__ int lastFlag;
    if (tid == 0){
        int t = __hip_atomic_fetch_add((int*)(p.ws + WS_TICK) + 1, 1,
                                       __ATOMIC_ACQ_REL, __HIP_MEMORY_SCOPE_AGENT);
        lastFlag = (t == (int)gridDim.x - 1);
    }
    __syncthreads();
    if (!lastFlag) return;

    // ---- tail: reduce part2 -> BN2 consts ----
    __shared__ float red2[8][32];
    {
        int c = tid & 31, seg = tid >> 5;
        int per = (p.nbp2 + 7) >> 3;
        float s = 0.f;
        for (int i = 0; i < per; ++i){
            int b = seg * per + i;
            if (b < p.nbp2)
                s += __hip_atomic_load(&part2[(long)b * 32 + c], __ATOMIC_RELAXED, __HIP_MEMORY_SCOPE_AGENT);
        }
        red2[seg][c] = s;
    }
    __syncthreads();
    if (tid < 9){
        float su = 0.f, sq = 0.f;
        #pragma unroll
        for (int q = 0; q < 8; ++q){ su += red2[q][tid]; sq += red2[q][9 + tid]; }
        const float invB = 1.f / (float)p.B;
        float mu  = su * invB;
        float var = fmaf(-mu, mu, sq * invB);
        float sc  = p.g2[tid] * __builtin_amdgcn_rsqf(var + BN_EPS);
        p.ws[WS_BN2S + tid] = sc;
        p.ws[WS_BN2H + tid] = fmaf(-mu, sc, p.be2[tid]);
    }
}

// ============ kB: BN2 + biLSTM x2 + output (round-6 proven) ============
template<int USE_WS>
__global__ __launch_bounds__(256) void kB(KParams p)
{
    const int tid = threadIdx.x;
    const float* ws = p.ws;
    const float* z2buf = ws + WS_Z2;
    const float* L1F = ws + WS_L1;          // w[8], u[16], b[8]
    const float* L1R = ws + WS_L1 + 32;
    const float* L2F = ws + WS_L2;          // W[16], U[4], b[4]
    const float* L2R = ws + WS_L2 + 24;

    long row = (long)blockIdx.x * 256 + tid;
    if (row >= p.B) return;

    // ---- a2 = relu(BN2(z2)) ----
    float a2[9];
    if (USE_WS){
        #pragma unroll
        for (int k = 0; k < 9; ++k){
            float z = z2buf[(long)k * p.B + row];
            a2[k] = relu_(fmaf(ws[WS_BN2S + k], z, ws[WS_BN2H + k]));
        }
    } else {
        float h0[9];
        load_h0(p.x, p.emb, row, h0);
        float a1[18];
        #pragma unroll
        for (int k = 0; k < 18; ++k){
            float s = ws[WS_B1P + k];
            #pragma unroll
            for (int j = 0; j < 9; ++j) s = fmaf(ws[WS_W1P + k*9 + j], h0[j], s);
            a1[k] = relu_(s);
        }
        #pragma unroll
        for (int k = 0; k < 9; ++k){
            float s = p.b2[k];
            #pragma unroll
            for (int j = 0; j < 18; ++j) s = fmaf(p.W2[k*18 + j], a1[j], s);
            a2[k] = relu_(fmaf(ws[WS_BN2S + k], s, ws[WS_BN2H + k]));
        }
    }

    // ---- biLSTM layer 1 (scalar, both dirs) ----
    float hf0 = 0.f, hf1 = 0.f, cf0 = 0.f, cf1 = 0.f;
    float hr0 = 0.f, hr1 = 0.f, cr0 = 0.f, cr1 = 0.f;
    float u_[9][4];
    #pragma unroll
    for (int s = 0; s < 9; ++s){
        const int tf = s, tr = 8 - s;
        float xf = a2[tf], xr = a2[tr];
        {
            const float* W = L1F; const float* U = L1F + 8; const float* Bb = L1F + 24;
            float zi0 = fmaf(W[0], xf, fmaf(U[0],  hf0, fmaf(U[1],  hf1, Bb[0])));
            float zi1 = fmaf(W[1], xf, fmaf(U[2],  hf0, fmaf(U[3],  hf1, Bb[1])));
            float zf0 = fmaf(W[2], xf, fmaf(U[4],  hf0, fmaf(U[5],  hf1, Bb[2])));
            float zf1 = fmaf(W[3], xf, fmaf(U[6],  hf0, fmaf(U[7],  hf1, Bb[3])));
            float zg0 = fmaf(W[4], xf, fmaf(U[8],  hf0, fmaf(U[9],  hf1, Bb[4])));
            float zg1 = fmaf(W[5], xf, fmaf(U[10], hf0, fmaf(U[11], hf1, Bb[5])));
            float zo0 = fmaf(W[6], xf, fmaf(U[12], hf0, fmaf(U[13], hf1, Bb[6])));
            float zo1 = fmaf(W[7], xf, fmaf(U[14], hf0, fmaf(U[15], hf1, Bb[7])));
            hf0 = cellh(zi0, zf0, zg0, zo0, cf0);
            hf1 = cellh(zi1, zf1, zg1, zo1, cf1);
        }
        {
            const float* W = L1R; const float* U = L1R + 8; const float* Bb = L1R + 24;
            float zi0 = fmaf(W[0], xr, fmaf(U[0],  hr0, fmaf(U[1],  hr1, Bb[0])));
            float zi1 = fmaf(W[1], xr, fmaf(U[2],  hr0, fmaf(U[3],  hr1, Bb[1])));
            float zf0 = fmaf(W[2], xr, fmaf(U[4],  hr0, fmaf(U[5],  hr1, Bb[2])));
            float zf1 = fmaf(W[3], xr, fmaf(U[6],  hr0, fmaf(U[7],  hr1, Bb[3])));
            float zg0 = fmaf(W[4], xr, fmaf(U[8],  hr0, fmaf(U[9],  hr1, Bb[4])));
            float zg1 = fmaf(W[5], xr, fmaf(U[10], hr0, fmaf(U[11], hr1, Bb[5])));
            float zo0 = fmaf(W[6], xr, fmaf(U[12], hr0, fmaf(U[13], hr1, Bb[6])));
            float zo1 = fmaf(W[7], xr, fmaf(U[14], hr0, fmaf(U[15], hr1, Bb[7])));
            hr0 = cellh(zi0, zf0, zg0, zo0, cr0);
            hr1 = cellh(zi1, zf1, zg1, zo1, cr1);
        }
        u_[tf][0] = relu_(hf0);
        u_[tf][1] = relu_(hf1);
        u_[tr][2] = relu_(hr0);
        u_[tr][3] = relu_(hr1);
    }

    // ---- biLSTM layer 2 (scalar, both dirs) ----
    float h2f = 0.f, c2f = 0.f, h2r = 0.f, c2r = 0.f;
    float of[9], orr[9];
    #pragma unroll
    for (int s = 0; s < 9; ++s){
        const int tf = s, tr = 8 - s;
        {
            const float* W = L2F; const float* U = L2F + 16; const float* Bb = L2F + 20;
            float zi = fmaf(W[0],  u_[tf][0], fmaf(W[1],  u_[tf][1], fmaf(W[2],  u_[tf][2], fmaf(W[3],  u_[tf][3], fmaf(U[0], h2f, Bb[0])))));
            float zf = fmaf(W[4],  u_[tf][0], fmaf(W[5],  u_[tf][1], fmaf(W[6],  u_[tf][2], fmaf(W[7],  u_[tf][3], fmaf(U[1], h2f, Bb[1])))));
            float zg = fmaf(W[8],  u_[tf][0], fmaf(W[9],  u_[tf][1], fmaf(W[10], u_[tf][2], fmaf(W[11], u_[tf][3], fmaf(U[2], h2f, Bb[2])))));
            float zo = fmaf(W[12], u_[tf][0], fmaf(W[13], u_[tf][1], fmaf(W[14], u_[tf][2], fmaf(W[15], u_[tf][3], fmaf(U[3], h2f, Bb[3])))));
            h2f = cellh(zi, zf, zg, zo, c2f);
            of[tf] = h2f;
        }
        {
            const float* W = L2R; const float* U = L2R + 16; const float* Bb = L2R + 20;
            float zi = fmaf(W[0],  u_[tr][0], fmaf(W[1],  u_[tr][1], fmaf(W[2],  u_[tr][2], fmaf(W[3],  u_[tr][3], fmaf(U[0], h2r, Bb[0])))));
            float zf = fmaf(W[4],  u_[tr][0], fmaf(W[5],  u_[tr][1], fmaf(W[6],  u_[tr][2], fmaf(W[7],  u_[tr][3], fmaf(U[1], h2r, Bb[1])))));
            float zg = fmaf(W[8],  u_[tr][0], fmaf(W[9],  u_[tr][1], fmaf(W[10], u_[tr][2], fmaf(W[11], u_[tr][3], fmaf(U[2], h2r, Bb[2])))));
            float zo = fmaf(W[12], u_[tr][0], fmaf(W[13], u_[tr][1], fmaf(W[14], u_[tr][2], fmaf(W[15], u_[tr][3], fmaf(U[3], h2r, Bb[3])))));
            h2r = cellh(zi, zf, zg, zo, c2r);
            orr[tr] = h2r;
        }
    }

    float2* op = (float2*)(p.out + row * 18);
    #pragma unroll
    for (int t = 0; t < 9; ++t) op[t] = make_float2(of[t], orr[t]);
}

extern "C" void kernel_launch(void* const* d_in, const int* in_sizes, int n_in,
                              void* d_out, int out_size, void* d_ws, size_t ws_size,
                              hipStream_t stream)
{
    KParams p;
    p.x    = (const float*)d_in[0];
    p.emb  = (const float*)d_in[1];
    p.W1   = (const float*)d_in[2];
    p.b1   = (const float*)d_in[3];
    p.g1   = (const float*)d_in[4];
    p.be1  = (const float*)d_in[5];
    p.W2   = (const float*)d_in[6];
    p.b2   = (const float*)d_in[7];
    p.g2   = (const float*)d_in[8];
    p.be2  = (const float*)d_in[9];
    p.w1f  = (const float*)d_in[10];
    p.u1f  = (const float*)d_in[11];
    p.c1f  = (const float*)d_in[12];
    p.w1r  = (const float*)d_in[13];
    p.u1r  = (const float*)d_in[14];
    p.c1r  = (const float*)d_in[15];
    p.w2f  = (const float*)d_in[16];
    p.u2f  = (const float*)d_in[17];
    p.c2f  = (const float*)d_in[18];
    p.w2r  = (const float*)d_in[19];
    p.u2r  = (const float*)d_in[20];
    p.c2r  = (const float*)d_in[21];
    p.ws   = (float*)d_ws;
    p.out  = (float*)d_out;
    p.B    = in_sizes[0] / 8;

    long t1 = ((long)p.B + 2047) / 2048;
    p.nbp1 = (int)(t1 > 512 ? 512 : t1);
    long t2 = ((long)p.B + 1023) / 1024;
    p.nbp2 = (int)(t2 > 1024 ? 1024 : t2);

    bool use_ws = ws_size >= (size_t)(WS_Z2 + 9 * (size_t)p.B) * sizeof(float);
    int nb1 = (p.B + 255) / 256;

    // zero the two tickets only
    hipMemsetAsync((char*)d_ws + WS_TICK * sizeof(float), 0, 8, stream);

    k1<<<p.nbp1, 256, 0, stream>>>(p);
    if (use_ws) k2<1><<<p.nbp2, 256, 0, stream>>>(p);
    else        k2<0><<<p.nbp2, 256, 0, stream>>>(p);
    if (use_ws) kB<1><<<nb1, 256, 0, stream>>>(p);
    else        kB<0><<<nb1, 256, 0, stream>>>(p);
}

// Round 9
// 153.064 us; speedup vs baseline: 2.2601x; 2.2601x over previous
//
#include <hip/hip_runtime.h>

#define LOG2E 1.4426950408889634f
#define BN_EPS 1e-5f

typedef float f32x2 __attribute__((ext_vector_type(2)));
typedef float f32x4 __attribute__((ext_vector_type(4)));

__device__ __forceinline__ float sigf(float x){
    return __builtin_amdgcn_rcpf(1.f + __builtin_amdgcn_exp2f(-LOG2E * x));
}
// sig(a)*tanh(b) with a single rcp: A=e^a, B=e^{2b} -> A(B-1)/((1+A)(B+1))
__device__ __forceinline__ float sigtanh(float a, float b){
    float A  = __builtin_amdgcn_exp2f(LOG2E * a);
    float Bv = __builtin_amdgcn_exp2f((2.f * LOG2E) * b);
    float num = A * (Bv - 1.f);
    float den = (1.f + A) * (1.f + Bv);
    return num * __builtin_amdgcn_rcpf(den);
}
__device__ __forceinline__ float relu_(float x){ return fmaxf(x, 0.f); }

__device__ __forceinline__ float wsum(float v){
    #pragma unroll
    for (int m = 32; m >= 1; m >>= 1) v += __shfl_xor(v, m, 64);
    return v;
}

__device__ constexpr int TRI(int j, int l){ return j*9 - j*(j-1)/2 + (l - j); } // j<=l, 45 entries

__device__ __forceinline__ void load_h0(const float* __restrict__ x, const float* __restrict__ emb,
                                        long row, float h0[9])
{
    const float4* xv = (const float4*)(x + row * 8);
    float4 p = xv[0];
    float4 q = xv[1];
    int idx = (int)p.x;
    float2 e = ((const float2*)emb)[idx];
    h0[0] = e.x; h0[1] = e.y;
    h0[2] = p.y; h0[3] = p.z; h0[4] = p.w;
    h0[5] = q.x; h0[6] = q.y; h0[7] = q.z; h0[8] = q.w;
}

// ---------------- Kernel 1: moments of h0 (9 sums + 45 second moments) ----------------
__global__ __launch_bounds__(256) void k_moments(const float* __restrict__ x, const float* __restrict__ emb,
                                                 float* __restrict__ stats, int B)
{
    float s9[9], mt[45];
    #pragma unroll
    for (int j = 0; j < 9; ++j) s9[j] = 0.f;
    #pragma unroll
    for (int t = 0; t < 45; ++t) mt[t] = 0.f;

    long base = (long)blockIdx.x * 1024 + threadIdx.x;
    #pragma unroll
    for (int r = 0; r < 4; ++r){
        long row = base + r * 256;
        if (row < B){
            float h0[9];
            load_h0(x, emb, row, h0);
            #pragma unroll
            for (int j = 0; j < 9; ++j){
                s9[j] += h0[j];
                #pragma unroll
                for (int l = j; l < 9; ++l)
                    mt[TRI(j,l)] = fmaf(h0[j], h0[l], mt[TRI(j,l)]);
            }
        }
    }
    __shared__ float sm[54];
    if (threadIdx.x < 54) sm[threadIdx.x] = 0.f;
    __syncthreads();
    bool l0 = (threadIdx.x & 63) == 0;
    #pragma unroll
    for (int j = 0; j < 9; ++j){
        float v = wsum(s9[j]);
        if (l0) atomicAdd(&sm[j], v);
    }
    #pragma unroll
    for (int t = 0; t < 45; ++t){
        float v = wsum(mt[t]);
        if (l0) atomicAdd(&sm[9 + t], v);
    }
    __syncthreads();
    if (threadIdx.x < 9)  atomicAdd(&stats[threadIdx.x], sm[threadIdx.x]);
    else if (threadIdx.x < 54) atomicAdd(&stats[16 + threadIdx.x - 9], sm[threadIdx.x]);
}

// BN1 scale/shift from moments; threads 0..17 -> LDS
__device__ __forceinline__ void bn1_from_moments(const float* __restrict__ stats,
                                                 const float* __restrict__ W1, const float* __restrict__ b1,
                                                 const float* __restrict__ g1, const float* __restrict__ be1,
                                                 float invB, float* smem_sc, float* smem_sh)
{
    if (threadIdx.x < 18){
        int k = threadIdx.x;
        float w[9];
        #pragma unroll
        for (int j = 0; j < 9; ++j) w[j] = W1[k*9 + j];
        float dot9 = 0.f, q = 0.f;
        #pragma unroll
        for (int j = 0; j < 9; ++j){
            dot9 = fmaf(w[j], stats[j], dot9);
            q = fmaf(w[j]*w[j], stats[16 + TRI(j,j)], q);
            #pragma unroll
            for (int l = j+1; l < 9; ++l)
                q = fmaf(2.f*w[j]*w[l], stats[16 + TRI(j,l)], q);
        }
        float m1  = dot9 * invB;
        float var = fmaf(-m1, m1, q * invB);
        float mu  = m1 + b1[k];
        float sc  = g1[k] * __builtin_amdgcn_rsqf(var + BN_EPS);
        smem_sc[k] = sc;
        smem_sh[k] = fmaf(-mu, sc, be1[k]);
    }
    __syncthreads();
}

// ---------------- Kernel 2: z2 stats (+ optional z2 cache) ----------------
template<int STORE_Z2>
__global__ __launch_bounds__(256) void k_stats2(const float* __restrict__ x, const float* __restrict__ emb,
                                                const float* __restrict__ W1, const float* __restrict__ b1,
                                                const float* __restrict__ g1, const float* __restrict__ be1,
                                                const float* __restrict__ W2, const float* __restrict__ b2,
                                                float* __restrict__ stats, float* __restrict__ z2buf, int B)
{
    __shared__ float s_sc[18], s_sh[18];
    bn1_from_moments(stats, W1, b1, g1, be1, 1.f/(float)B, s_sc, s_sh);

    float sc1[18], sh1[18];
    #pragma unroll
    for (int k = 0; k < 18; ++k){ sc1[k] = s_sc[k]; sh1[k] = s_sh[k]; }

    float as[9], aq[9];
    #pragma unroll
    for (int k = 0; k < 9; ++k){ as[k] = 0.f; aq[k] = 0.f; }

    long base = (long)blockIdx.x * 1024 + threadIdx.x;
    #pragma unroll
    for (int r = 0; r < 4; ++r){
        long row = base + r * 256;
        if (row < B){
            float h0[9];
            load_h0(x, emb, row, h0);
            float a1[18];
            #pragma unroll
            for (int k = 0; k < 18; ++k){
                float s = b1[k];
                #pragma unroll
                for (int j = 0; j < 9; ++j) s = fmaf(W1[k*9 + j], h0[j], s);
                a1[k] = relu_(fmaf(sc1[k], s, sh1[k]));
            }
            #pragma unroll
            for (int k = 0; k < 9; ++k){
                float s = b2[k];
                #pragma unroll
                for (int j = 0; j < 18; ++j) s = fmaf(W2[k*18 + j], a1[j], s);
                as[k] += s; aq[k] = fmaf(s, s, aq[k]);
                if (STORE_Z2) z2buf[(long)k * B + row] = s;
            }
        }
    }
    __shared__ float sm[18];
    if (threadIdx.x < 18) sm[threadIdx.x] = 0.f;
    __syncthreads();
    bool l0 = (threadIdx.x & 63) == 0;
    #pragma unroll
    for (int k = 0; k < 9; ++k){
        float s = wsum(as[k]);
        float q = wsum(aq[k]);
        if (l0){ atomicAdd(&sm[k], s); atomicAdd(&sm[9 + k], q); }
    }
    __syncthreads();
    if (threadIdx.x < 9)       atomicAdd(&stats[64 + threadIdx.x], sm[threadIdx.x]);
    else if (threadIdx.x < 18) atomicAdd(&stats[80 + threadIdx.x - 9], sm[threadIdx.x]);
}

__device__ __forceinline__ f32x2 mk2(float a, float b){ f32x2 r; r.x=a; r.y=b; return r; }
__device__ __forceinline__ f32x4 mk4(float a, float b, float c, float d){ f32x4 r; r.x=a; r.y=b; r.z=c; r.w=d; return r; }

// ---------------- Kernel 3: BN2 + biLSTM x2 + output ----------------
template<int USE_WS>
__global__ __launch_bounds__(256) void k_main(const float* __restrict__ x, const float* __restrict__ emb,
    const float* __restrict__ W1, const float* __restrict__ b1,
    const float* __restrict__ g1, const float* __restrict__ be1,
    const float* __restrict__ W2, const float* __restrict__ b2,
    const float* __restrict__ g2, const float* __restrict__ be2,
    const float* __restrict__ w1f, const float* __restrict__ u1f, const float* __restrict__ c1f,
    const float* __restrict__ w1r, const float* __restrict__ u1r, const float* __restrict__ c1r,
    const float* __restrict__ w2f, const float* __restrict__ u2f, const float* __restrict__ c2f,
    const float* __restrict__ w2r, const float* __restrict__ u2r, const float* __restrict__ c2r,
    const float* __restrict__ stats, const float* __restrict__ z2buf,
    float* __restrict__ out, int B)
{
    __shared__ float s_sc[18], s_sh[18];
    float invB = 1.f / (float)B;
    if (!USE_WS) bn1_from_moments(stats, W1, b1, g1, be1, invB, s_sc, s_sh);

    long row = (long)blockIdx.x * 256 + threadIdx.x;
    if (row >= B) return;

    // ---- a2 = relu(BN2(z2)) ----
    float a2[9];
    #pragma unroll
    for (int k = 0; k < 9; ++k){
        float zc;
        if (USE_WS){
            zc = z2buf[(long)k * B + row];
        } else {
            zc = 0.f; // computed below
        }
        a2[k] = zc;
    }
    if (!USE_WS){
        float h0[9];
        load_h0(x, emb, row, h0);
        float a1[18];
        #pragma unroll
        for (int k = 0; k < 18; ++k){
            float s = b1[k];
            #pragma unroll
            for (int j = 0; j < 9; ++j) s = fmaf(W1[k*9 + j], h0[j], s);
            a1[k] = relu_(fmaf(s_sc[k], s, s_sh[k]));
        }
        #pragma unroll
        for (int k = 0; k < 9; ++k){
            float s = b2[k];
            #pragma unroll
            for (int j = 0; j < 18; ++j) s = fmaf(W2[k*18 + j], a1[j], s);
            a2[k] = s;
        }
    }
    #pragma unroll
    for (int k = 0; k < 9; ++k){
        float mu  = stats[64 + k] * invB;
        float var = fmaf(-mu, mu, stats[80 + k] * invB);
        float sc  = g2[k] * __builtin_amdgcn_rsqf(var + BN_EPS);
        a2[k] = relu_(fmaf(sc, a2[k] - mu, be2[k]));
    }

    // ---- biLSTM layer 1, packed [fwd0, fwd1, rev0, rev1] ----
    f32x4 W4[4], U04[4], U14[4], B4[4];
    #pragma unroll
    for (int g = 0; g < 4; ++g){
        W4[g]  = mk4(w1f[2*g], w1f[2*g+1], w1r[2*g], w1r[2*g+1]);
        U04[g] = mk4(u1f[(2*g)*2], u1f[(2*g+1)*2], u1r[(2*g)*2], u1r[(2*g+1)*2]);
        U14[g] = mk4(u1f[(2*g)*2+1], u1f[(2*g+1)*2+1], u1r[(2*g)*2+1], u1r[(2*g+1)*2+1]);
        B4[g]  = mk4(c1f[2*g], c1f[2*g+1], c1r[2*g], c1r[2*g+1]);
    }
    f32x4 h4 = {0.f, 0.f, 0.f, 0.f};
    f32x4 c4 = {0.f, 0.f, 0.f, 0.f};
    float u_[9][4];
    #pragma unroll
    for (int s = 0; s < 9; ++s){
        const int tf = s, tr = 8 - s;
        f32x4 xt4 = mk4(a2[tf], a2[tf], a2[tr], a2[tr]);
        f32x4 hx  = mk4(h4.x, h4.x, h4.z, h4.z);
        f32x4 hy  = mk4(h4.y, h4.y, h4.w, h4.w);
        f32x4 z[4];
        #pragma unroll
        for (int g = 0; g < 4; ++g)
            z[g] = __builtin_elementwise_fma(W4[g], xt4,
                    __builtin_elementwise_fma(U04[g], hx,
                     __builtin_elementwise_fma(U14[g], hy, B4[g])));
        f32x4 icg, fs;
        #pragma unroll
        for (int c = 0; c < 4; ++c){
            icg[c] = sigtanh(z[0][c], z[2][c]);
            fs[c]  = sigf(z[1][c]);
        }
        c4 = __builtin_elementwise_fma(fs, c4, icg);
        #pragma unroll
        for (int c = 0; c < 4; ++c) h4[c] = sigtanh(z[3][c], c4[c]);
        u_[tf][0] = relu_(h4.x);
        u_[tf][1] = relu_(h4.y);
        u_[tr][2] = relu_(h4.z);
        u_[tr][3] = relu_(h4.w);
    }

    // ---- biLSTM layer 2, packed [fwd, rev] ----
    f32x2 w2v[4][4], u2v[4], b2v[4];
    #pragma unroll
    for (int r = 0; r < 4; ++r){
        #pragma unroll
        for (int j = 0; j < 4; ++j) w2v[r][j] = mk2(w2f[4*r + j], w2r[4*r + j]);
        u2v[r] = mk2(u2f[r], u2r[r]);
        b2v[r] = mk2(c2f[r], c2r[r]);
    }
    f32x2 h2 = {0.f, 0.f};
    f32x2 cc = {0.f, 0.f};
    long obase = row * 18;
    #pragma unroll
    for (int s = 0; s < 9; ++s){
        const int tf = s, tr = 8 - s;
        f32x2 z[4];
        #pragma unroll
        for (int r = 0; r < 4; ++r){
            f32x2 acc = __builtin_elementwise_fma(u2v[r], h2, b2v[r]);
            #pragma unroll
            for (int j = 0; j < 4; ++j)
                acc = __builtin_elementwise_fma(w2v[r][j], mk2(u_[tf][j], u_[tr][j]), acc);
            z[r] = acc;
        }
        f32x2 icg, fs;
        #pragma unroll
        for (int c = 0; c < 2; ++c){
            icg[c] = sigtanh(z[0][c], z[2][c]);
            fs[c]  = sigf(z[1][c]);
        }
        cc = __builtin_elementwise_fma(fs, cc, icg);
        float hfo = sigtanh(z[3][0], cc.x);
        float hro = sigtanh(z[3][1], cc.y);
        h2 = mk2(hfo, hro);
        out[obase + 2*tf]     = hfo;
        out[obase + 2*tr + 1] = hro;
    }
}

extern "C" void kernel_launch(void* const* d_in, const int* in_sizes, int n_in,
                              void* d_out, int out_size, void* d_ws, size_t ws_size,
                              hipStream_t stream)
{
    const float* x    = (const float*)d_in[0];
    const float* emb  = (const float*)d_in[1];
    const float* W1   = (const float*)d_in[2];
    const float* b1   = (const float*)d_in[3];
    const float* g1   = (const float*)d_in[4];
    const float* be1  = (const float*)d_in[5];
    const float* W2   = (const float*)d_in[6];
    const float* b2   = (const float*)d_in[7];
    const float* g2   = (const float*)d_in[8];
    const float* be2  = (const float*)d_in[9];
    const float* l1Wf = (const float*)d_in[10];
    const float* l1Uf = (const float*)d_in[11];
    const float* l1bf = (const float*)d_in[12];
    const float* l1Wr = (const float*)d_in[13];
    const float* l1Ur = (const float*)d_in[14];
    const float* l1br = (const float*)d_in[15];
    const float* l2Wf = (const float*)d_in[16];
    const float* l2Uf = (const float*)d_in[17];
    const float* l2bf = (const float*)d_in[18];
    const float* l2Wr = (const float*)d_in[19];
    const float* l2Ur = (const float*)d_in[20];
    const float* l2br = (const float*)d_in[21];

    int B = in_sizes[0] / 8;
    float* stats = (float*)d_ws;
    float* z2buf = (float*)d_ws + 1024;
    size_t need = (1024 + (size_t)9 * B) * sizeof(float);
    bool use_ws = ws_size >= need;

    // stats layout: [0:9] sum h0, [16:61] upper-tri second moments,
    //               [64:73] sum z2, [80:89] sumsq z2
    hipMemsetAsync(d_ws, 0, 128 * sizeof(float), stream);

    int nb12 = (B + 1023) / 1024;
    int nb3  = (B + 255) / 256;

    k_moments<<<nb12, 256, 0, stream>>>(x, emb, stats, B);
    if (use_ws){
        k_stats2<1><<<nb12, 256, 0, stream>>>(x, emb, W1, b1, g1, be1, W2, b2, stats, z2buf, B);
        k_main<1><<<nb3, 256, 0, stream>>>(x, emb, W1, b1, g1, be1, W2, b2, g2, be2,
                                           l1Wf, l1Uf, l1bf, l1Wr, l1Ur, l1br,
                                           l2Wf, l2Uf, l2bf, l2Wr, l2Ur, l2br,
                                           stats, z2buf, (float*)d_out, B);
    } else {
        k_stats2<0><<<nb12, 256, 0, stream>>>(x, emb, W1, b1, g1, be1, W2, b2, stats, z2buf, B);
        k_main<0><<<nb3, 256, 0, stream>>>(x, emb, W1, b1, g1, be1, W2, b2, g2, be2,
                                           l1Wf, l1Uf, l1bf, l1Wr, l1Ur, l1br,
                                           l2Wf, l2Uf, l2bf, l2Wr, l2Ur, l2br,
                                           stats, z2buf, (float*)d_out, B);
    }
}